// Round 3
// baseline (529.439 us; speedup 1.0000x reference)
//
#include <hip/hip_runtime.h>
#include <cstdint>
#include <cstddef>

typedef unsigned short ushort_t;
typedef __bf16 bf16x8 __attribute__((ext_vector_type(8)));
typedef float f32x4 __attribute__((ext_vector_type(4)));

__device__ __forceinline__ float b2f(ushort_t u) {
    return __uint_as_float(((unsigned int)u) << 16);
}
__device__ __forceinline__ ushort_t f2b(float f) {
    __bf16 h = (__bf16)f;  // RNE
    return *(ushort_t*)&h;
}

// stage 8 contiguous elements into LDS as bf16 (overloaded on source type)
__device__ __forceinline__ void stage8(const float* __restrict__ g, ushort_t* s) {
    float4 f0 = *(const float4*)g;
    float4 f1 = *(const float4*)(g + 4);
    union { ushort_t u[8]; uint4 v; } t;
    t.u[0] = f2b(f0.x); t.u[1] = f2b(f0.y); t.u[2] = f2b(f0.z); t.u[3] = f2b(f0.w);
    t.u[4] = f2b(f1.x); t.u[5] = f2b(f1.y); t.u[6] = f2b(f1.z); t.u[7] = f2b(f1.w);
    *(uint4*)s = t.v;
}
__device__ __forceinline__ void stage8(const ushort_t* __restrict__ g, ushort_t* s) {
    *(float4*)s = *(const float4*)g;  // already bf16: raw 16B copy
}

// ---------------- weight transpose+convert: WT[n][k] = bf16(W[k][n]) ----------------
__global__ __launch_bounds__(256) void transpose_kernel(const float* __restrict__ W,
                                                        ushort_t* __restrict__ WT,
                                                        int K, int N2) {
    int id = blockIdx.x * 256 + threadIdx.x;
    if (id >= K * N2) return;
    int n = id / K, k = id - n * K;
    WT[id] = f2b(W[k * N2 + n]);
}

// ---------------- CSR build ----------------
__global__ __launch_bounds__(256) void degree_kernel(const int* __restrict__ ei_dst,
                                                     int* __restrict__ deg, int E, int Etot) {
    int e = blockIdx.x * 256 + threadIdx.x;
    if (e >= Etot) return;
    int d = (e < E) ? ei_dst[e] : (e - E);
    atomicAdd(&deg[d], 1);
}

// pass 1: per-block (256-wide tile) sum of deg -> bsum[b]
__global__ __launch_bounds__(256) void partial_sum_kernel(const int* __restrict__ deg,
                                                          int* __restrict__ bsum, int n) {
    __shared__ int ws[4];
    int t = threadIdx.x;
    int i = blockIdx.x * 256 + t;
    int v = (i < n) ? deg[i] : 0;
#pragma unroll
    for (int off = 32; off; off >>= 1) v += __shfl_xor(v, off, 64);
    if ((t & 63) == 0) ws[t >> 6] = v;
    __syncthreads();
    if (t == 0) bsum[blockIdx.x] = ws[0] + ws[1] + ws[2] + ws[3];
}

// pass 2: single block scans up to 256 block sums -> exclusive boff[b]; writes rowoff[n]=total
__global__ __launch_bounds__(256) void scan_bsum_kernel(const int* __restrict__ bsum,
                                                        int* __restrict__ boff,
                                                        int* __restrict__ rowoff,
                                                        int nblk, int n) {
    __shared__ int sm[256];
    int t = threadIdx.x;
    int v = (t < nblk) ? bsum[t] : 0;
    sm[t] = v;
    __syncthreads();
#pragma unroll
    for (int off = 1; off < 256; off <<= 1) {
        int u = (t >= off) ? sm[t - off] : 0;
        __syncthreads();
        sm[t] += u;
        __syncthreads();
    }
    if (t < nblk) boff[t] = sm[t] - v;   // exclusive prefix
    if (t == 255) rowoff[n] = sm[255];   // grand total
}

// pass 3: per-block inclusive scan + block offset -> exclusive rowoff[i]
__global__ __launch_bounds__(256) void block_scan_kernel(const int* __restrict__ deg,
                                                         const int* __restrict__ boff,
                                                         int* __restrict__ rowoff, int n) {
    __shared__ int sm[256];
    int t = threadIdx.x;
    int i = blockIdx.x * 256 + t;
    int v = (i < n) ? deg[i] : 0;
    sm[t] = v;
    __syncthreads();
#pragma unroll
    for (int off = 1; off < 256; off <<= 1) {
        int u = (t >= off) ? sm[t - off] : 0;
        __syncthreads();
        sm[t] += u;
        __syncthreads();
    }
    if (i < n) rowoff[i] = boff[blockIdx.x] + sm[t] - v;  // exclusive
}

// cursor[i] = rowoff[i] (sequential copy; lets scatter skip the random rowoff read)
__global__ __launch_bounds__(256) void copy_cursor_kernel(const int* __restrict__ rowoff,
                                                          int* __restrict__ cursor, int n) {
    int i = blockIdx.x * 256 + threadIdx.x;
    if (i < n) cursor[i] = rowoff[i];
}

// sdst[i] = d for i in [rowoff[d], rowoff[d+1]) — sequential writes, no scatter
__global__ __launch_bounds__(256) void fill_sdst_kernel(const int* __restrict__ rowoff,
                                                        int* __restrict__ sdst, int n) {
    int d = blockIdx.x * 256 + threadIdx.x;
    if (d >= n) return;
    int a = rowoff[d], b = rowoff[d + 1];
    for (int i = a; i < b; i++) sdst[i] = d;
}

// one random atomic + one random write per edge (rowoff read folded into cursor init)
__global__ __launch_bounds__(256) void scatter_kernel(const int* __restrict__ ei_src,
                                                      const int* __restrict__ ei_dst,
                                                      int* __restrict__ cursor,
                                                      int* __restrict__ ssrc, int E, int Etot) {
    int e = blockIdx.x * 256 + threadIdx.x;
    if (e >= Etot) return;
    int s, d;
    if (e < E) { s = ei_src[e]; d = ei_dst[e]; } else { s = d = e - E; }
    int pos = atomicAdd(&cursor[d], 1);
    ssrc[pos] = s;
}

// ---------------- per-edge softmax weights (hoisted out of aggregation) ----------------
template <int H>
__global__ __launch_bounds__(256) void edge_p_kernel(const int* __restrict__ ssrc,
                                                     const int* __restrict__ sdst,
                                                     const float* __restrict__ as_n,
                                                     const float* __restrict__ ad_n,
                                                     float* __restrict__ p, int Etot) {
    int id = blockIdx.x * 256 + threadIdx.x;
    if (H == 4) {
        if (id >= Etot * 4) return;
        int e = id >> 2, h = id & 3;
        int s = ssrc[e], d = sdst[e];
        float lg = as_n[s * 4 + h] + ad_n[d * 4 + h];
        lg = lg > 0.f ? lg : 0.2f * lg;
        p[id] = __expf(lg);
    } else {
        if (id >= Etot) return;
        int s = ssrc[id], d = sdst[id];
        float lg = as_n[s] + ad_n[d];
        lg = lg > 0.f ? lg : 0.2f * lg;
        p[id] = __expf(lg);
    }
}

// ---------------- MFMA GEMM: C = A[M,K] @ WT[N2,K]^T ----------------
// BM=64, BN=64, BK=32; 256 thr = 4 waves; wave w owns rows w*16..w*16+15.
template <typename TA, bool EPI>
__global__ __launch_bounds__(256) void gemm_mfma(const TA* __restrict__ A,
                                                 const ushort_t* __restrict__ WT,
                                                 float* __restrict__ C,
                                                 ushort_t* __restrict__ Cb,
                                                 const float* __restrict__ bias,
                                                 int M, int K, int N2) {
    __shared__ ushort_t sA[64 * 32];  // 4 KB
    __shared__ ushort_t sB[64 * 32];  // 4 KB
    const int tid = threadIdx.x;
    const int wv = tid >> 6, lane = tid & 63;
    const int quad = lane >> 4, l16 = lane & 15;
    const int bm = blockIdx.x * 64, bn = blockIdx.y * 64;
    const int srow = tid >> 2, skof = (tid & 3) * 8;
    f32x4 acc[4] = {};

    for (int k0 = 0; k0 < K; k0 += 32) {
        int gm = bm + srow;
        gm = gm < M ? gm : M - 1;  // clamp tail (dup read; epilogue masks)
        stage8(A + (size_t)gm * K + k0 + skof, sA + srow * 32 + skof);
        stage8(WT + (size_t)(bn + srow) * K + k0 + skof, sB + srow * 32 + skof);
        __syncthreads();

        bf16x8 af = *(const bf16x8*)(sA + (wv * 16 + l16) * 32 + quad * 8);
#pragma unroll
        for (int j = 0; j < 4; j++) {
            bf16x8 bf = *(const bf16x8*)(sB + (j * 16 + l16) * 32 + quad * 8);
            acc[j] = __builtin_amdgcn_mfma_f32_16x16x32_bf16(af, bf, acc[j], 0, 0, 0);
        }
        __syncthreads();
    }

#pragma unroll
    for (int j = 0; j < 4; j++) {
        int col = bn + j * 16 + l16;
        float bv = EPI ? bias[col] : 0.f;
#pragma unroll
        for (int r = 0; r < 4; r++) {
            int row = bm + wv * 16 + quad * 4 + r;
            if (row < M) {
                float v = acc[j][r];
                if (EPI) {
                    v += bv;
                    v = v > 0.f ? v : 0.f;
                    C[(size_t)row * N2 + col] = v;
                } else {
                    Cb[(size_t)row * N2 + col] = f2b(v);
                }
            }
        }
    }
}

// ---------------- attention coefficients ----------------
template <int CH>
__global__ __launch_bounds__(256) void attn_kernel(const ushort_t* __restrict__ xl,
                                                   const float* __restrict__ a_src,
                                                   const float* __restrict__ a_dst,
                                                   float* __restrict__ as_n,
                                                   float* __restrict__ ad_n, int N) {
    int n = blockIdx.x * 4 + (threadIdx.x >> 6);
    int lane = threadIdx.x & 63;
    if (n >= N) return;
    if (CH == 256) {
        ushort4 u = ((const ushort4*)xl)[(size_t)n * 64 + lane];
        float4 av = ((const float4*)a_src)[lane];
        float4 dv = ((const float4*)a_dst)[lane];
        float x0 = b2f(u.x), x1 = b2f(u.y), x2 = b2f(u.z), x3 = b2f(u.w);
        float s = x0 * av.x + x1 * av.y + x2 * av.z + x3 * av.w;
        float d = x0 * dv.x + x1 * dv.y + x2 * dv.z + x3 * dv.w;
#pragma unroll
        for (int off = 8; off; off >>= 1) {
            s += __shfl_xor(s, off, 64);
            d += __shfl_xor(d, off, 64);
        }
        if ((lane & 15) == 0) {
            int h = lane >> 4;
            as_n[n * 4 + h] = s;
            ad_n[n * 4 + h] = d;
        }
    } else {
        float xv = b2f(xl[(size_t)n * 64 + lane]);
        float s = xv * a_src[lane];
        float d = xv * a_dst[lane];
#pragma unroll
        for (int off = 32; off; off >>= 1) {
            s += __shfl_xor(s, off, 64);
            d += __shfl_xor(d, off, 64);
        }
        if (lane == 0) { as_n[n] = s; ad_n[n] = d; }
    }
}

// ---------------- per-dst softmax-weighted aggregation (p precomputed; unroll-8) ----------------
// CH=256: lane l owns channels 4l..4l+3 (head l>>4). Inner loop: ssrc + p + row gather + FMA only.
// Unroll 8 with clamp-and-zero: OOB slots clamp to r0 (valid row, L1-hit dup), p=0 kills them.
template <int CH>
__global__ __launch_bounds__(256) void aggregate_kernel(const ushort_t* __restrict__ xl,
                                                        const float* __restrict__ pp,
                                                        const int* __restrict__ rowoff,
                                                        const int* __restrict__ ssrc,
                                                        const float* __restrict__ bias,
                                                        ushort_t* __restrict__ hout, int N) {
    int dd = blockIdx.x * 4 + (threadIdx.x >> 6);
    int lane = threadIdx.x & 63;
    if (dd >= N) return;
    int r0 = rowoff[dd], r1 = rowoff[dd + 1];
    if (CH == 256) {
        const int h = lane >> 4;
        const ushort4* xv = (const ushort4*)xl;
        float a0 = 0.f, a1 = 0.f, a2 = 0.f, a3 = 0.f, den = 0.f;
        for (int i = r0; i < r1; i += 8) {
            int idx[8];
            float pv[8];
            ushort4 u[8];
#pragma unroll
            for (int j = 0; j < 8; j++) {
                int t = i + j;
                int id2 = t < r1 ? t : r0;
                idx[j] = ssrc[id2];
                float pw = pp[id2 * 4 + h];
                pv[j] = t < r1 ? pw : 0.f;
            }
#pragma unroll
            for (int j = 0; j < 8; j++) u[j] = xv[(size_t)idx[j] * 64 + lane];
#pragma unroll
            for (int j = 0; j < 8; j++) {
                den += pv[j];
                a0 += pv[j] * b2f(u[j].x);
                a1 += pv[j] * b2f(u[j].y);
                a2 += pv[j] * b2f(u[j].z);
                a3 += pv[j] * b2f(u[j].w);
            }
        }
        float di = 1.f / (den + 1e-16f);
        float4 bv = ((const float4*)bias)[lane];
        float v0 = a0 * di + bv.x;
        float v1 = a1 * di + bv.y;
        float v2 = a2 * di + bv.z;
        float v3 = a3 * di + bv.w;
        ushort4 o;
        o.x = f2b(v0 > 0.f ? v0 : 0.f);
        o.y = f2b(v1 > 0.f ? v1 : 0.f);
        o.z = f2b(v2 > 0.f ? v2 : 0.f);
        o.w = f2b(v3 > 0.f ? v3 : 0.f);
        ((ushort4*)hout)[(size_t)dd * 64 + lane] = o;
    } else {
        float a0 = 0.f, den = 0.f;
        for (int i = r0; i < r1; i += 8) {
            int idx[8];
            float pv[8];
            ushort_t u[8];
#pragma unroll
            for (int j = 0; j < 8; j++) {
                int t = i + j;
                int id2 = t < r1 ? t : r0;
                idx[j] = ssrc[id2];
                float pw = pp[id2];
                pv[j] = t < r1 ? pw : 0.f;
            }
#pragma unroll
            for (int j = 0; j < 8; j++) u[j] = xl[(size_t)idx[j] * 64 + lane];
#pragma unroll
            for (int j = 0; j < 8; j++) {
                den += pv[j];
                a0 += pv[j] * b2f(u[j]);
            }
        }
        float v = a0 / (den + 1e-16f) + bias[lane];
        hout[(size_t)dd * 64 + lane] = f2b(v > 0.f ? v : 0.f);
    }
}

extern "C" void kernel_launch(void* const* d_in, const int* in_sizes, int n_in,
                              void* d_out, int out_size, void* d_ws, size_t ws_size,
                              hipStream_t stream) {
    const int N = in_sizes[0] / 128;  // 50000
    const int E = in_sizes[1] / 2;    // 800000
    const int Etot = E + N;

    const float* x = (const float*)d_in[0];  // fp32 input
    const int* ei = (const int*)d_in[1];
    const int* ei_src = ei;
    const int* ei_dst = ei + E;
    float* out = (float*)d_out;  // fp32 output

    const float* as1 = (const float*)d_in[3];
    const float* ad1 = (const float*)d_in[4];
    const float* b1  = (const float*)d_in[5];
    const float* as2 = (const float*)d_in[7];
    const float* ad2 = (const float*)d_in[8];
    const float* b2  = (const float*)d_in[9];
    const float* as3 = (const float*)d_in[11];
    const float* ad3 = (const float*)d_in[12];
    const float* b3  = (const float*)d_in[13];
    const float* bfc = (const float*)d_in[15];

    // ---- workspace layout (bf16 activations) ----
    ushort_t* bufX = (ushort_t*)d_ws;            // [N][256] bf16 (xl, GEMM out)
    ushort_t* bufH = bufX + (size_t)N * 256;     // [N][256] bf16 (agg out)
    ushort_t* W1T  = bufH + (size_t)N * 256;     // 256x128 bf16
    ushort_t* W2T  = W1T + 32768;                // 256x256
    ushort_t* W3T  = W2T + 65536;                // 64x256
    ushort_t* WfcT = W3T + 16384;                // 512x64
    float* asn = (float*)(WfcT + 32768);         // N*4
    float* adn = asn + (size_t)N * 4;            // N*4
    int* deg    = (int*)(adn + (size_t)N * 4);   // N
    int* rowoff = deg + N;                       // N+1
    int* cursor = rowoff + N + 1;                // N
    int* ssrc   = cursor + N;                    // Etot
    int* sdst   = ssrc + Etot;                   // Etot
    int* bsum   = sdst + Etot;                   // <=256 (scan pass 1)
    int* boff   = bsum + 256;                    // <=256 (scan pass 2)
    float* pbuf = (float*)(boff + 256);          // Etot*4 (edge softmax weights)

    // weight transposes+converts (fp32 [K][N] -> bf16 [N][K])
    transpose_kernel<<<(128 * 256 + 255) / 256, 256, 0, stream>>>((const float*)d_in[2], W1T, 128, 256);
    transpose_kernel<<<(256 * 256 + 255) / 256, 256, 0, stream>>>((const float*)d_in[6], W2T, 256, 256);
    transpose_kernel<<<(256 * 64 + 255) / 256, 256, 0, stream>>>((const float*)d_in[10], W3T, 256, 64);
    transpose_kernel<<<(64 * 512 + 255) / 256, 256, 0, stream>>>((const float*)d_in[14], WfcT, 64, 512);

    // CSR build
    hipMemsetAsync(deg, 0, (size_t)N * sizeof(int), stream);
    int eb = (Etot + 255) / 256;
    degree_kernel<<<eb, 256, 0, stream>>>(ei_dst, deg, E, Etot);
    // parallel 3-pass exclusive scan of deg -> rowoff
    const int NBLK = (N + 255) / 256;  // 196 (must be <= 256)
    partial_sum_kernel<<<NBLK, 256, 0, stream>>>(deg, bsum, N);
    scan_bsum_kernel<<<1, 256, 0, stream>>>(bsum, boff, rowoff, NBLK, N);
    block_scan_kernel<<<NBLK, 256, 0, stream>>>(deg, boff, rowoff, N);
    // cursor := rowoff (so scatter needs no rowoff read); sdst from CSR structure (no scatter)
    copy_cursor_kernel<<<NBLK, 256, 0, stream>>>(rowoff, cursor, N);
    fill_sdst_kernel<<<NBLK, 256, 0, stream>>>(rowoff, sdst, N);
    scatter_kernel<<<eb, 256, 0, stream>>>(ei_src, ei_dst, cursor, ssrc, E, Etot);

    const int MB = (N + 63) / 64;  // 782
    int nb4 = (N + 3) / 4;
    int epb4 = (Etot * 4 + 255) / 256;
    int epb1 = (Etot + 255) / 256;

    // layer 1: x(fp32) @ W1 -> bufX(bf16); attn; edge p; aggregate -> bufH(bf16)
    gemm_mfma<float, false><<<dim3(MB, 4), 256, 0, stream>>>(x, W1T, nullptr, bufX, nullptr, N, 128, 256);
    attn_kernel<256><<<nb4, 256, 0, stream>>>(bufX, as1, ad1, asn, adn, N);
    edge_p_kernel<4><<<epb4, 256, 0, stream>>>(ssrc, sdst, asn, adn, pbuf, Etot);
    aggregate_kernel<256><<<nb4, 256, 0, stream>>>(bufX, pbuf, rowoff, ssrc, b1, bufH, N);

    // layer 2
    gemm_mfma<ushort_t, false><<<dim3(MB, 4), 256, 0, stream>>>(bufH, W2T, nullptr, bufX, nullptr, N, 256, 256);
    attn_kernel<256><<<nb4, 256, 0, stream>>>(bufX, as2, ad2, asn, adn, N);
    edge_p_kernel<4><<<epb4, 256, 0, stream>>>(ssrc, sdst, asn, adn, pbuf, Etot);
    aggregate_kernel<256><<<nb4, 256, 0, stream>>>(bufX, pbuf, rowoff, ssrc, b2, bufH, N);

    // layer 3 (H=1, C=64)
    gemm_mfma<ushort_t, false><<<dim3(MB, 1), 256, 0, stream>>>(bufH, W3T, nullptr, bufX, nullptr, N, 256, 64);
    attn_kernel<64><<<nb4, 256, 0, stream>>>(bufX, as3, ad3, asn, adn, N);
    edge_p_kernel<1><<<epb1, 256, 0, stream>>>(ssrc, sdst, asn, adn, pbuf, Etot);
    aggregate_kernel<64><<<nb4, 256, 0, stream>>>(bufX, pbuf, rowoff, ssrc, b3, bufH, N);

    // final fc: relu(bufH[N,64] @ Wfc + bfc) -> fp32 out
    gemm_mfma<ushort_t, true><<<dim3(MB, 8), 256, 0, stream>>>(bufH, WfcT, out, nullptr, bfc, N, 64, 512);
}

// Round 4
// 496.741 us; speedup vs baseline: 1.0658x; 1.0658x over previous
//
#include <hip/hip_runtime.h>
#include <cstdint>
#include <cstddef>

typedef unsigned short ushort_t;
typedef __bf16 bf16x8 __attribute__((ext_vector_type(8)));
typedef float f32x4 __attribute__((ext_vector_type(4)));

__device__ __forceinline__ float b2f(ushort_t u) {
    return __uint_as_float(((unsigned int)u) << 16);
}
__device__ __forceinline__ ushort_t f2b(float f) {
    __bf16 h = (__bf16)f;  // RNE
    return *(ushort_t*)&h;
}
// bf16 pair unpack from packed uint (little-endian: lo ushort = even channel)
__device__ __forceinline__ float lo16(unsigned int u) { return __uint_as_float(u << 16); }
__device__ __forceinline__ float hi16(unsigned int u) { return __uint_as_float(u & 0xffff0000u); }
__device__ __forceinline__ unsigned int pack2(float a, float b) {
    return ((unsigned int)f2b(b) << 16) | (unsigned int)f2b(a);
}

// stage 8 contiguous elements into LDS as bf16 (overloaded on source type)
__device__ __forceinline__ void stage8(const float* __restrict__ g, ushort_t* s) {
    float4 f0 = *(const float4*)g;
    float4 f1 = *(const float4*)(g + 4);
    union { ushort_t u[8]; uint4 v; } t;
    t.u[0] = f2b(f0.x); t.u[1] = f2b(f0.y); t.u[2] = f2b(f0.z); t.u[3] = f2b(f0.w);
    t.u[4] = f2b(f1.x); t.u[5] = f2b(f1.y); t.u[6] = f2b(f1.z); t.u[7] = f2b(f1.w);
    *(uint4*)s = t.v;
}
__device__ __forceinline__ void stage8(const ushort_t* __restrict__ g, ushort_t* s) {
    *(float4*)s = *(const float4*)g;  // already bf16: raw 16B copy
}

// ---------------- weight transpose+convert: WT[n][k] = bf16(W[k][n]) ----------------
__global__ __launch_bounds__(256) void transpose_kernel(const float* __restrict__ W,
                                                        ushort_t* __restrict__ WT,
                                                        int K, int N2) {
    int id = blockIdx.x * 256 + threadIdx.x;
    if (id >= K * N2) return;
    int n = id / K, k = id - n * K;
    WT[id] = f2b(W[k * N2 + n]);
}

// ---------------- CSR build ----------------
__global__ __launch_bounds__(256) void degree_kernel(const int* __restrict__ ei_dst,
                                                     int* __restrict__ deg, int E, int Etot) {
    int e = blockIdx.x * 256 + threadIdx.x;
    if (e >= Etot) return;
    int d = (e < E) ? ei_dst[e] : (e - E);
    atomicAdd(&deg[d], 1);
}

// pass 1: per-block (256-wide tile) sum of deg -> bsum[b]
__global__ __launch_bounds__(256) void partial_sum_kernel(const int* __restrict__ deg,
                                                          int* __restrict__ bsum, int n) {
    __shared__ int ws[4];
    int t = threadIdx.x;
    int i = blockIdx.x * 256 + t;
    int v = (i < n) ? deg[i] : 0;
#pragma unroll
    for (int off = 32; off; off >>= 1) v += __shfl_xor(v, off, 64);
    if ((t & 63) == 0) ws[t >> 6] = v;
    __syncthreads();
    if (t == 0) bsum[blockIdx.x] = ws[0] + ws[1] + ws[2] + ws[3];
}

// pass 2: single block scans up to 256 block sums -> exclusive boff[b]; writes rowoff[n]=total
__global__ __launch_bounds__(256) void scan_bsum_kernel(const int* __restrict__ bsum,
                                                        int* __restrict__ boff,
                                                        int* __restrict__ rowoff,
                                                        int nblk, int n) {
    __shared__ int sm[256];
    int t = threadIdx.x;
    int v = (t < nblk) ? bsum[t] : 0;
    sm[t] = v;
    __syncthreads();
#pragma unroll
    for (int off = 1; off < 256; off <<= 1) {
        int u = (t >= off) ? sm[t - off] : 0;
        __syncthreads();
        sm[t] += u;
        __syncthreads();
    }
    if (t < nblk) boff[t] = sm[t] - v;   // exclusive prefix
    if (t == 255) rowoff[n] = sm[255];   // grand total
}

// pass 3: per-block inclusive scan + block offset -> exclusive rowoff[i]
__global__ __launch_bounds__(256) void block_scan_kernel(const int* __restrict__ deg,
                                                         const int* __restrict__ boff,
                                                         int* __restrict__ rowoff, int n) {
    __shared__ int sm[256];
    int t = threadIdx.x;
    int i = blockIdx.x * 256 + t;
    int v = (i < n) ? deg[i] : 0;
    sm[t] = v;
    __syncthreads();
#pragma unroll
    for (int off = 1; off < 256; off <<= 1) {
        int u = (t >= off) ? sm[t - off] : 0;
        __syncthreads();
        sm[t] += u;
        __syncthreads();
    }
    if (i < n) rowoff[i] = boff[blockIdx.x] + sm[t] - v;  // exclusive
}

// cursor[i] = rowoff[i] (sequential copy; lets scatter skip the random rowoff read)
__global__ __launch_bounds__(256) void copy_cursor_kernel(const int* __restrict__ rowoff,
                                                          int* __restrict__ cursor, int n) {
    int i = blockIdx.x * 256 + threadIdx.x;
    if (i < n) cursor[i] = rowoff[i];
}

// one random atomic + one random write per edge
__global__ __launch_bounds__(256) void scatter_kernel(const int* __restrict__ ei_src,
                                                      const int* __restrict__ ei_dst,
                                                      int* __restrict__ cursor,
                                                      int* __restrict__ ssrc, int E, int Etot) {
    int e = blockIdx.x * 256 + threadIdx.x;
    if (e >= Etot) return;
    int s, d;
    if (e < E) { s = ei_src[e]; d = ei_dst[e]; } else { s = d = e - E; }
    int pos = atomicAdd(&cursor[d], 1);
    ssrc[pos] = s;
}

// ---------------- MFMA GEMM: C = A[M,K] @ WT[N2,K]^T ----------------
// BM=64, BN=64, BK=32; 256 thr = 4 waves; wave w owns rows w*16..w*16+15.
template <typename TA, bool EPI>
__global__ __launch_bounds__(256) void gemm_mfma(const TA* __restrict__ A,
                                                 const ushort_t* __restrict__ WT,
                                                 float* __restrict__ C,
                                                 ushort_t* __restrict__ Cb,
                                                 const float* __restrict__ bias,
                                                 int M, int K, int N2) {
    __shared__ ushort_t sA[64 * 32];  // 4 KB
    __shared__ ushort_t sB[64 * 32];  // 4 KB
    const int tid = threadIdx.x;
    const int wv = tid >> 6, lane = tid & 63;
    const int quad = lane >> 4, l16 = lane & 15;
    const int bm = blockIdx.x * 64, bn = blockIdx.y * 64;
    const int srow = tid >> 2, skof = (tid & 3) * 8;
    f32x4 acc[4] = {};

    for (int k0 = 0; k0 < K; k0 += 32) {
        int gm = bm + srow;
        gm = gm < M ? gm : M - 1;  // clamp tail (dup read; epilogue masks)
        stage8(A + (size_t)gm * K + k0 + skof, sA + srow * 32 + skof);
        stage8(WT + (size_t)(bn + srow) * K + k0 + skof, sB + srow * 32 + skof);
        __syncthreads();

        bf16x8 af = *(const bf16x8*)(sA + (wv * 16 + l16) * 32 + quad * 8);
#pragma unroll
        for (int j = 0; j < 4; j++) {
            bf16x8 bf = *(const bf16x8*)(sB + (j * 16 + l16) * 32 + quad * 8);
            acc[j] = __builtin_amdgcn_mfma_f32_16x16x32_bf16(af, bf, acc[j], 0, 0, 0);
        }
        __syncthreads();
    }

#pragma unroll
    for (int j = 0; j < 4; j++) {
        int col = bn + j * 16 + l16;
        float bv = EPI ? bias[col] : 0.f;
#pragma unroll
        for (int r = 0; r < 4; r++) {
            int row = bm + wv * 16 + quad * 4 + r;
            if (row < M) {
                float v = acc[j][r];
                if (EPI) {
                    v += bv;
                    v = v > 0.f ? v : 0.f;
                    C[(size_t)row * N2 + col] = v;
                } else {
                    Cb[(size_t)row * N2 + col] = f2b(v);
                }
            }
        }
    }
}

// ---------------- attention coefficients ----------------
template <int CH>
__global__ __launch_bounds__(256) void attn_kernel(const ushort_t* __restrict__ xl,
                                                   const float* __restrict__ a_src,
                                                   const float* __restrict__ a_dst,
                                                   float* __restrict__ as_n,
                                                   float* __restrict__ ad_n, int N) {
    int n = blockIdx.x * 4 + (threadIdx.x >> 6);
    int lane = threadIdx.x & 63;
    if (n >= N) return;
    if (CH == 256) {
        ushort4 u = ((const ushort4*)xl)[(size_t)n * 64 + lane];
        float4 av = ((const float4*)a_src)[lane];
        float4 dv = ((const float4*)a_dst)[lane];
        float x0 = b2f(u.x), x1 = b2f(u.y), x2 = b2f(u.z), x3 = b2f(u.w);
        float s = x0 * av.x + x1 * av.y + x2 * av.z + x3 * av.w;
        float d = x0 * dv.x + x1 * dv.y + x2 * dv.z + x3 * dv.w;
#pragma unroll
        for (int off = 8; off; off >>= 1) {
            s += __shfl_xor(s, off, 64);
            d += __shfl_xor(d, off, 64);
        }
        if ((lane & 15) == 0) {
            int h = lane >> 4;
            as_n[n * 4 + h] = s;
            ad_n[n * 4 + h] = d;
        }
    } else {
        float xv = b2f(xl[(size_t)n * 64 + lane]);
        float s = xv * a_src[lane];
        float d = xv * a_dst[lane];
#pragma unroll
        for (int off = 32; off; off >>= 1) {
            s += __shfl_xor(s, off, 64);
            d += __shfl_xor(d, off, 64);
        }
        if (lane == 0) { as_n[n] = s; ad_n[n] = d; }
    }
}

// ---------------- per-dst softmax-weighted aggregation (wide-gather, fused p) ----------------
// CH=256: 32 lanes/dst (lane=8ch, dwordx4 gather), 2 dst/wave -> 1024B fetched per gather instr,
//         8 instrs in flight = 16 edge-rows. p computed inline (as_n is L2-resident, 800KB).
// CH=64: 8 lanes/dst (16B), 8 dst/wave.
// Clamp-and-zero padding: OOB slots clamp to r0 (L1-hit dup), p=0 kills contribution.
template <int CH>
__global__ __launch_bounds__(256) void aggregate_kernel(const ushort_t* __restrict__ xl,
                                                        const float* __restrict__ as_n,
                                                        const float* __restrict__ ad_n,
                                                        const int* __restrict__ rowoff,
                                                        const int* __restrict__ ssrc,
                                                        const float* __restrict__ bias,
                                                        ushort_t* __restrict__ hout, int N) {
    const int tid = threadIdx.x;
    const int wv = tid >> 6, lane = tid & 63;
    const uint4* xv = (const uint4*)xl;
    if (CH == 256) {
        const int hw = lane >> 5, l32 = lane & 31;
        const int dd = blockIdx.x * 8 + wv * 2 + hw;
        if (dd >= N) return;
        const int h = l32 >> 3;  // head of my 8 channels
        const int r0 = rowoff[dd], r1 = rowoff[dd + 1];
        const float adv = ad_n[dd * 4 + h];
        float a0 = 0, a1 = 0, a2 = 0, a3 = 0, a4 = 0, a5 = 0, a6 = 0, a7 = 0, den = 0;
        for (int i = r0; i < r1; i += 8) {
            int s[8];
            float g[8];
            uint4 u[8];
#pragma unroll
            for (int j = 0; j < 8; j++) {
                int t = i + j;
                s[j] = ssrc[t < r1 ? t : r0];
            }
#pragma unroll
            for (int j = 0; j < 8; j++) g[j] = as_n[s[j] * 4 + h];
#pragma unroll
            for (int j = 0; j < 8; j++) u[j] = xv[(size_t)s[j] * 32 + l32];
#pragma unroll
            for (int j = 0; j < 8; j++) {
                float lg = g[j] + adv;
                lg = lg > 0.f ? lg : 0.2f * lg;
                float p = (i + j < r1) ? __expf(lg) : 0.f;
                den += p;
                a0 += p * lo16(u[j].x); a1 += p * hi16(u[j].x);
                a2 += p * lo16(u[j].y); a3 += p * hi16(u[j].y);
                a4 += p * lo16(u[j].z); a5 += p * hi16(u[j].z);
                a6 += p * lo16(u[j].w); a7 += p * hi16(u[j].w);
            }
        }
        float di = 1.f / (den + 1e-16f);
        float4 b0 = ((const float4*)bias)[l32 * 2];
        float4 b1 = ((const float4*)bias)[l32 * 2 + 1];
        float v0 = a0 * di + b0.x, v1 = a1 * di + b0.y;
        float v2 = a2 * di + b0.z, v3 = a3 * di + b0.w;
        float v4 = a4 * di + b1.x, v5 = a5 * di + b1.y;
        float v6 = a6 * di + b1.z, v7 = a7 * di + b1.w;
        v0 = v0 > 0.f ? v0 : 0.f; v1 = v1 > 0.f ? v1 : 0.f;
        v2 = v2 > 0.f ? v2 : 0.f; v3 = v3 > 0.f ? v3 : 0.f;
        v4 = v4 > 0.f ? v4 : 0.f; v5 = v5 > 0.f ? v5 : 0.f;
        v6 = v6 > 0.f ? v6 : 0.f; v7 = v7 > 0.f ? v7 : 0.f;
        uint4 o;
        o.x = pack2(v0, v1); o.y = pack2(v2, v3);
        o.z = pack2(v4, v5); o.w = pack2(v6, v7);
        ((uint4*)hout)[(size_t)dd * 32 + l32] = o;
    } else {
        const int grp = lane >> 3, l8 = lane & 7;
        const int dd = blockIdx.x * 32 + wv * 8 + grp;
        if (dd >= N) return;
        const int r0 = rowoff[dd], r1 = rowoff[dd + 1];
        const float adv = ad_n[dd];
        float a0 = 0, a1 = 0, a2 = 0, a3 = 0, a4 = 0, a5 = 0, a6 = 0, a7 = 0, den = 0;
        for (int i = r0; i < r1; i += 8) {
            int s[8];
            float g[8];
            uint4 u[8];
#pragma unroll
            for (int j = 0; j < 8; j++) {
                int t = i + j;
                s[j] = ssrc[t < r1 ? t : r0];
            }
#pragma unroll
            for (int j = 0; j < 8; j++) g[j] = as_n[s[j]];
#pragma unroll
            for (int j = 0; j < 8; j++) u[j] = xv[(size_t)s[j] * 8 + l8];
#pragma unroll
            for (int j = 0; j < 8; j++) {
                float lg = g[j] + adv;
                lg = lg > 0.f ? lg : 0.2f * lg;
                float p = (i + j < r1) ? __expf(lg) : 0.f;
                den += p;
                a0 += p * lo16(u[j].x); a1 += p * hi16(u[j].x);
                a2 += p * lo16(u[j].y); a3 += p * hi16(u[j].y);
                a4 += p * lo16(u[j].z); a5 += p * hi16(u[j].z);
                a6 += p * lo16(u[j].w); a7 += p * hi16(u[j].w);
            }
        }
        float di = 1.f / (den + 1e-16f);
        float4 b0 = ((const float4*)bias)[l8 * 2];
        float4 b1 = ((const float4*)bias)[l8 * 2 + 1];
        float v0 = a0 * di + b0.x, v1 = a1 * di + b0.y;
        float v2 = a2 * di + b0.z, v3 = a3 * di + b0.w;
        float v4 = a4 * di + b1.x, v5 = a5 * di + b1.y;
        float v6 = a6 * di + b1.z, v7 = a7 * di + b1.w;
        v0 = v0 > 0.f ? v0 : 0.f; v1 = v1 > 0.f ? v1 : 0.f;
        v2 = v2 > 0.f ? v2 : 0.f; v3 = v3 > 0.f ? v3 : 0.f;
        v4 = v4 > 0.f ? v4 : 0.f; v5 = v5 > 0.f ? v5 : 0.f;
        v6 = v6 > 0.f ? v6 : 0.f; v7 = v7 > 0.f ? v7 : 0.f;
        uint4 o;
        o.x = pack2(v0, v1); o.y = pack2(v2, v3);
        o.z = pack2(v4, v5); o.w = pack2(v6, v7);
        ((uint4*)hout)[(size_t)dd * 8 + l8] = o;
    }
}

extern "C" void kernel_launch(void* const* d_in, const int* in_sizes, int n_in,
                              void* d_out, int out_size, void* d_ws, size_t ws_size,
                              hipStream_t stream) {
    const int N = in_sizes[0] / 128;  // 50000
    const int E = in_sizes[1] / 2;    // 800000
    const int Etot = E + N;

    const float* x = (const float*)d_in[0];  // fp32 input
    const int* ei = (const int*)d_in[1];
    const int* ei_src = ei;
    const int* ei_dst = ei + E;
    float* out = (float*)d_out;  // fp32 output

    const float* as1 = (const float*)d_in[3];
    const float* ad1 = (const float*)d_in[4];
    const float* b1  = (const float*)d_in[5];
    const float* as2 = (const float*)d_in[7];
    const float* ad2 = (const float*)d_in[8];
    const float* b2  = (const float*)d_in[9];
    const float* as3 = (const float*)d_in[11];
    const float* ad3 = (const float*)d_in[12];
    const float* b3  = (const float*)d_in[13];
    const float* bfc = (const float*)d_in[15];

    // ---- workspace layout (bf16 activations) ----
    ushort_t* bufX = (ushort_t*)d_ws;            // [N][256] bf16 (xl, GEMM out)
    ushort_t* bufH = bufX + (size_t)N * 256;     // [N][256] bf16 (agg out)
    ushort_t* W1T  = bufH + (size_t)N * 256;     // 256x128 bf16
    ushort_t* W2T  = W1T + 32768;                // 256x256
    ushort_t* W3T  = W2T + 65536;                // 64x256
    ushort_t* WfcT = W3T + 16384;                // 512x64
    float* asn = (float*)(WfcT + 32768);         // N*4
    float* adn = asn + (size_t)N * 4;            // N*4
    int* deg    = (int*)(adn + (size_t)N * 4);   // N
    int* rowoff = deg + N;                       // N+1
    int* cursor = rowoff + N + 1;                // N
    int* ssrc   = cursor + N;                    // Etot
    int* bsum   = ssrc + Etot;                   // <=256 (scan pass 1)
    int* boff   = bsum + 256;                    // <=256 (scan pass 2)

    // weight transposes+converts (fp32 [K][N] -> bf16 [N][K])
    transpose_kernel<<<(128 * 256 + 255) / 256, 256, 0, stream>>>((const float*)d_in[2], W1T, 128, 256);
    transpose_kernel<<<(256 * 256 + 255) / 256, 256, 0, stream>>>((const float*)d_in[6], W2T, 256, 256);
    transpose_kernel<<<(256 * 64 + 255) / 256, 256, 0, stream>>>((const float*)d_in[10], W3T, 256, 64);
    transpose_kernel<<<(64 * 512 + 255) / 256, 256, 0, stream>>>((const float*)d_in[14], WfcT, 64, 512);

    // CSR build
    hipMemsetAsync(deg, 0, (size_t)N * sizeof(int), stream);
    int eb = (Etot + 255) / 256;
    degree_kernel<<<eb, 256, 0, stream>>>(ei_dst, deg, E, Etot);
    // parallel 3-pass exclusive scan of deg -> rowoff
    const int NBLK = (N + 255) / 256;  // 196 (must be <= 256)
    partial_sum_kernel<<<NBLK, 256, 0, stream>>>(deg, bsum, N);
    scan_bsum_kernel<<<1, 256, 0, stream>>>(bsum, boff, rowoff, NBLK, N);
    block_scan_kernel<<<NBLK, 256, 0, stream>>>(deg, boff, rowoff, N);
    copy_cursor_kernel<<<NBLK, 256, 0, stream>>>(rowoff, cursor, N);
    scatter_kernel<<<eb, 256, 0, stream>>>(ei_src, ei_dst, cursor, ssrc, E, Etot);

    const int MB = (N + 63) / 64;   // 782
    int nb4 = (N + 3) / 4;
    int nb8 = (N + 7) / 8;
    int nb32 = (N + 31) / 32;

    // layer 1: x(fp32) @ W1 -> bufX(bf16); attn; aggregate(fused p) -> bufH(bf16)
    gemm_mfma<float, false><<<dim3(MB, 4), 256, 0, stream>>>(x, W1T, nullptr, bufX, nullptr, N, 128, 256);
    attn_kernel<256><<<nb4, 256, 0, stream>>>(bufX, as1, ad1, asn, adn, N);
    aggregate_kernel<256><<<nb8, 256, 0, stream>>>(bufX, asn, adn, rowoff, ssrc, b1, bufH, N);

    // layer 2
    gemm_mfma<ushort_t, false><<<dim3(MB, 4), 256, 0, stream>>>(bufH, W2T, nullptr, bufX, nullptr, N, 256, 256);
    attn_kernel<256><<<nb4, 256, 0, stream>>>(bufX, as2, ad2, asn, adn, N);
    aggregate_kernel<256><<<nb8, 256, 0, stream>>>(bufX, asn, adn, rowoff, ssrc, b2, bufH, N);

    // layer 3 (H=1, C=64)
    gemm_mfma<ushort_t, false><<<dim3(MB, 1), 256, 0, stream>>>(bufH, W3T, nullptr, bufX, nullptr, N, 256, 64);
    attn_kernel<64><<<nb4, 256, 0, stream>>>(bufX, as3, ad3, asn, adn, N);
    aggregate_kernel<64><<<nb32, 256, 0, stream>>>(bufX, asn, adn, rowoff, ssrc, b3, bufH, N);

    // final fc: relu(bufH[N,64] @ Wfc + bfc) -> fp32 out
    gemm_mfma<ushort_t, true><<<dim3(MB, 8), 256, 0, stream>>>(bufH, WfcT, out, nullptr, bfc, N, 64, 512);
}